// Round 1
// baseline (272.065 us; speedup 1.0000x reference)
//
#include <hip/hip_runtime.h>
#include <cstdint>
#include <cstddef>

// Problem constants
#define NB    32   // batch
#define NC1   64   // in channels
#define NC2   128  // out channels
#define NE    4    // routed experts
#define NSLOT 5    // 4 experts + shared
#define HIN   64
#define WIN   64
#define HOUT  32
#define WOUT  32

// ws layout (float offsets)
#define GATEIN_OFF 0                      // [32][64]
#define GATES_OFF  2048                   // [32][4]
#define WT_OFF     2176                   // [5][64][9][128] transposed weights
#define BIAS_OFF   (2176 + 368640)        // [5][128]
#define GAMMA_OFF  (BIAS_OFF + 640)       // [5][128]
#define BETA_OFF   (GAMMA_OFF + 640)      // [5][128]
// total floats = BETA_OFF + 640 = 372736  (~1.49 MB)

// ---------------------------------------------------------------------------
// Kernel A: repack weights -> wT[slot][c][tap][c2], pack bias/gamma/beta
// ---------------------------------------------------------------------------
__global__ void prep_kernel(const float* __restrict__ expert_w,
                            const float* __restrict__ shared_w,
                            const float* __restrict__ expert_b,
                            const float* __restrict__ shared_b,
                            const float* __restrict__ eln_w,
                            const float* __restrict__ sln_w,
                            const float* __restrict__ eln_b,
                            const float* __restrict__ sln_b,
                            float* __restrict__ ws) {
    int i = blockIdx.x * 256 + threadIdx.x;
    if (i < NSLOT * NC1 * 9 * NC2) {
        int c2 = i & 127;
        int k  = (i >> 7) % 9;
        int c  = (i / (128 * 9)) & 63;
        int e  = i / (128 * 9 * 64);
        float v;
        if (e < NE) v = expert_w[(((size_t)(e * NC2 + c2) * NC1 + c) * 9) + k];
        else        v = shared_w[(((size_t)c2 * NC1 + c) * 9) + k];
        ws[WT_OFF + i] = v;
    }
    if (i < NSLOT * NC2) {
        int e = i >> 7, c2 = i & 127;
        ws[BIAS_OFF  + i] = (e < NE) ? expert_b[i] : shared_b[c2];
        ws[GAMMA_OFF + i] = (e < NE) ? eln_w[i]    : sln_w[c2];
        ws[BETA_OFF  + i] = (e < NE) ? eln_b[i]    : sln_b[c2];
    }
}

// ---------------------------------------------------------------------------
// Kernel B: gate_in[b][c] = mean over HxW of x.  One wave per (b,c).
// ---------------------------------------------------------------------------
__global__ void gatein_kernel(const float* __restrict__ x, float* __restrict__ ws) {
    int bid  = blockIdx.x;          // b*64 + c
    int lane = threadIdx.x;         // 0..63
    const float* src = x + (size_t)bid * (HIN * WIN);
    float s = 0.f;
    for (int i = lane * 4; i < HIN * WIN; i += 64 * 4) {
        float4 v = *(const float4*)(src + i);
        s += v.x + v.y + v.z + v.w;
    }
    #pragma unroll
    for (int off = 32; off >= 1; off >>= 1) s += __shfl_xor(s, off);
    if (lane == 0) ws[GATEIN_OFF + bid] = s * (1.f / (HIN * WIN));
}

// ---------------------------------------------------------------------------
// Kernel C: logits -> top2 -> softmax -> dense gates[b][4]
// ---------------------------------------------------------------------------
__global__ void gate_kernel(const float* __restrict__ w_gate, float* __restrict__ ws) {
    int b = threadIdx.x;
    if (b >= NB) return;
    const float* gi = ws + GATEIN_OFF + b * NC1;
    float l[NE] = {0.f, 0.f, 0.f, 0.f};
    for (int c = 0; c < NC1; ++c) {
        float v = gi[c];
        #pragma unroll
        for (int e = 0; e < NE; ++e) l[e] += v * w_gate[c * NE + e];
    }
    // top-2 (first occurrence on ties, matching lax.top_k)
    int i0 = 0; float v0 = l[0];
    #pragma unroll
    for (int e = 1; e < NE; ++e) if (l[e] > v0) { v0 = l[e]; i0 = e; }
    int i1 = -1; float v1 = -3.4e38f;
    #pragma unroll
    for (int e = 0; e < NE; ++e) if (e != i0 && l[e] > v1) { v1 = l[e]; i1 = e; }
    float e1 = expf(v1 - v0);
    float denom = 1.f + e1;
    float g0 = 1.f / denom, g1 = e1 / denom;
    #pragma unroll
    for (int e = 0; e < NE; ++e)
        ws[GATES_OFF + b * NE + e] = (e == i0) ? g0 : ((e == i1) ? g1 : 0.f);
}

// ---------------------------------------------------------------------------
// Kernel D: fused conv + LN + gate-weighted combine (+ shared expert)
// Block = (b, h'). 256 threads.
//   thread t: pair = t&63 -> channels c2 = 2*pair, 2*pair+1
//             wgrp = t>>6 -> w' = wgrp*8 .. wgrp*8+7
// Each wave (one wgrp) covers all 128 channels -> LN = in-wave shfl reduce.
// ---------------------------------------------------------------------------
#define XROW 68   // padded LDS row stride (floats); 68*4=272B = 17*16B aligned

__global__ __launch_bounds__(256, 2) void fused_kernel(
        const float* __restrict__ x,
        const float* __restrict__ ws,
        float* __restrict__ out) {
    __shared__ float lds_x[NC1 * 3 * XROW];   // 52224 B

    const int bid = blockIdx.x;        // 0..1023
    const int b   = bid >> 5;
    const int hp  = bid & 31;          // h'
    const int tid = threadIdx.x;

    // ---- stage 3 input rows (2h'-1 .. 2h'+1), 64 channels, zero-pad col 0 ----
    for (int idx = tid; idx < NC1 * 3 * 17; idx += 256) {
        int c   = idx / 51;
        int rem = idx - c * 51;
        int r   = rem / 17;
        int i4  = rem - r * 17;
        int hin = 2 * hp - 1 + r;
        float vv[4] = {0.f, 0.f, 0.f, 0.f};
        if (hin >= 0) {   // hin <= 63 always
            const float* src = x + (((size_t)b * NC1 + c) * HIN + hin) * WIN;
            #pragma unroll
            for (int k = 0; k < 4; ++k) {
                int p = i4 * 4 + k;     // lds col; p==0 is the w=-1 zero pad
                vv[k] = (p >= 1 && p <= WIN) ? src[p - 1] : 0.f;
            }
        }
        *(float4*)&lds_x[(c * 3 + r) * XROW + i4 * 4] =
            make_float4(vv[0], vv[1], vv[2], vv[3]);
    }
    __syncthreads();

    const int pair = tid & 63;
    const int wgrp = tid >> 6;
    const int c2   = pair * 2;
    const int w0   = wgrp * 8;

    const float* wT     = ws + WT_OFF;
    const float* bias5  = ws + BIAS_OFF;
    const float* gamma5 = ws + GAMMA_OFF;
    const float* beta5  = ws + BETA_OFF;
    const float* gates  = ws + GATES_OFF;

    float acc0[8] = {0,0,0,0,0,0,0,0};
    float acc1[8] = {0,0,0,0,0,0,0,0};

    for (int s = 0; s < NSLOT; ++s) {
        float g = (s < NE) ? gates[b * NE + s] : 1.0f;
        if (g == 0.f) continue;

        float y0[8] = {0,0,0,0,0,0,0,0};
        float y1[8] = {0,0,0,0,0,0,0,0};
        const float* wtE = wT + (size_t)s * NC1 * 9 * NC2;

        for (int c = 0; c < NC1; ++c) {
            float2 wv[9];
            const float* wb = wtE + c * 9 * NC2 + c2;
            #pragma unroll
            for (int k = 0; k < 9; ++k) wv[k] = *(const float2*)(wb + k * NC2);
            #pragma unroll
            for (int r = 0; r < 3; ++r) {
                const float* xr = &lds_x[(c * 3 + r) * XROW + 2 * w0];
                float xv[17];
                #pragma unroll
                for (int q = 0; q < 4; ++q)
                    *(float4*)&xv[q * 4] = *(const float4*)&xr[q * 4];
                xv[16] = xr[16];
                #pragma unroll
                for (int j = 0; j < 8; ++j) {
                    #pragma unroll
                    for (int kw = 0; kw < 3; ++kw) {
                        float xx = xv[2 * j + kw];
                        y0[j] = fmaf(xx, wv[r * 3 + kw].x, y0[j]);
                        y1[j] = fmaf(xx, wv[r * 3 + kw].y, y1[j]);
                    }
                }
            }
        }

        // bias + LayerNorm over 128 channels (in-wave: 2 ch/lane x 64 lanes)
        float b0 = bias5[s * NC2 + c2],     b1 = bias5[s * NC2 + c2 + 1];
        float gm0 = gamma5[s * NC2 + c2],   gm1 = gamma5[s * NC2 + c2 + 1];
        float bt0 = beta5[s * NC2 + c2],    bt1 = beta5[s * NC2 + c2 + 1];
        #pragma unroll
        for (int j = 0; j < 8; ++j) {
            float a0 = y0[j] + b0;
            float a1 = y1[j] + b1;
            float sum = a0 + a1;
            float sq  = a0 * a0 + a1 * a1;
            #pragma unroll
            for (int off = 32; off >= 1; off >>= 1) {
                sum += __shfl_xor(sum, off);
                sq  += __shfl_xor(sq,  off);
            }
            float mean = sum * (1.f / NC2);
            float var  = sq * (1.f / NC2) - mean * mean;
            float rstd = rsqrtf(var + 1e-6f);
            acc0[j] = fmaf(g, gm0 * ((a0 - mean) * rstd) + bt0, acc0[j]);
            acc1[j] = fmaf(g, gm1 * ((a1 - mean) * rstd) + bt1, acc1[j]);
        }
    }

    // ---- store: out[b][c2][h'][w0..w0+7], two channels per thread ----
    float* op = out + (((size_t)b * NC2 + c2) * HOUT + hp) * WOUT + w0;
    *(float4*)(op)     = make_float4(acc0[0], acc0[1], acc0[2], acc0[3]);
    *(float4*)(op + 4) = make_float4(acc0[4], acc0[5], acc0[6], acc0[7]);
    op += HOUT * WOUT;
    *(float4*)(op)     = make_float4(acc1[0], acc1[1], acc1[2], acc1[3]);
    *(float4*)(op + 4) = make_float4(acc1[4], acc1[5], acc1[6], acc1[7]);
}

// ---------------------------------------------------------------------------
extern "C" void kernel_launch(void* const* d_in, const int* in_sizes, int n_in,
                              void* d_out, int out_size, void* d_ws, size_t ws_size,
                              hipStream_t stream) {
    const float* x        = (const float*)d_in[0];
    const float* w_gate   = (const float*)d_in[1];
    const float* expert_w = (const float*)d_in[2];
    const float* expert_b = (const float*)d_in[3];
    const float* eln_w    = (const float*)d_in[4];
    const float* eln_b    = (const float*)d_in[5];
    const float* shared_w = (const float*)d_in[6];
    const float* shared_b = (const float*)d_in[7];
    const float* sln_w    = (const float*)d_in[8];
    const float* sln_b    = (const float*)d_in[9];
    float* ws  = (float*)d_ws;
    float* out = (float*)d_out;

    // A: repack weights/params (368640 elems / 256 = 1440 blocks exactly)
    prep_kernel<<<1440, 256, 0, stream>>>(expert_w, shared_w, expert_b, shared_b,
                                          eln_w, sln_w, eln_b, sln_b, ws);
    // B: gate_in means (one wave per (b,c))
    gatein_kernel<<<NB * NC1, 64, 0, stream>>>(x, ws);
    // C: gating
    gate_kernel<<<1, 64, 0, stream>>>(w_gate, ws);
    // D: fused conv+LN+combine
    fused_kernel<<<NB * HOUT, 256, 0, stream>>>(x, ws, out);
}

// Round 2
// 87.070 us; speedup vs baseline: 3.1247x; 3.1247x over previous
//
#include <hip/hip_runtime.h>
#include <cstdint>
#include <cstddef>

// Problem constants
#define NB    32
#define NC1   64
#define NC2   128
#define NE    4
#define NSLOT 5
#define HIN   64
#define WIN   64
#define HOUT  32
#define WOUT  32

// ws layout (float offsets)
#define GATEIN_OFF 0        // [32][64] f32
#define GATES_OFF  2048     // [32][4]  f32
#define BIAS_OFF   2176     // [5][128] f32
#define GAMMA_OFF  2816     // [5][128] f32
#define BETA_OFF   3456     // [5][128] f32
#define WBF_OFF    4096     // [5][9][128][64] bf16 (368640 elems = 184320 f32 slots)

typedef __bf16 bf16x8 __attribute__((ext_vector_type(8)));
typedef float  f32x16 __attribute__((ext_vector_type(16)));

// ---------------------------------------------------------------------------
// Kernel A: repack weights -> bf16 wA[slot][tap][c2][c]; pack bias/gamma/beta
// ---------------------------------------------------------------------------
__global__ void prep_kernel(const float* __restrict__ expert_w,
                            const float* __restrict__ shared_w,
                            const float* __restrict__ expert_b,
                            const float* __restrict__ shared_b,
                            const float* __restrict__ eln_w,
                            const float* __restrict__ sln_w,
                            const float* __restrict__ eln_b,
                            const float* __restrict__ sln_b,
                            float* __restrict__ ws) {
    int i = blockIdx.x * 256 + threadIdx.x;
    if (i < NSLOT * 9 * NC2 * NC1) {
        int c   = i & 63;
        int c2  = (i >> 6) & 127;
        int tap = (i >> 13) % 9;
        int e   = i / (NC1 * NC2 * 9);
        float v;
        if (e < NE) v = expert_w[(((size_t)(e * NC2 + c2) * NC1 + c) * 9) + tap];
        else        v = shared_w[(((size_t)c2 * NC1 + c) * 9) + tap];
        ((__bf16*)(ws + WBF_OFF))[i] = (__bf16)v;
    }
    if (i < NSLOT * NC2) {
        int e = i >> 7, c2 = i & 127;
        ws[BIAS_OFF  + i] = (e < NE) ? expert_b[i] : shared_b[c2];
        ws[GAMMA_OFF + i] = (e < NE) ? eln_w[i]    : sln_w[c2];
        ws[BETA_OFF  + i] = (e < NE) ? eln_b[i]    : sln_b[c2];
    }
}

// ---------------------------------------------------------------------------
// Kernel B: gate_in[b][c] = mean over HxW.  One wave per (b,c).
// ---------------------------------------------------------------------------
__global__ void gatein_kernel(const float* __restrict__ x, float* __restrict__ ws) {
    int bid  = blockIdx.x;
    int lane = threadIdx.x;
    const float* src = x + (size_t)bid * (HIN * WIN);
    float s = 0.f;
    for (int i = lane * 4; i < HIN * WIN; i += 64 * 4) {
        float4 v = *(const float4*)(src + i);
        s += v.x + v.y + v.z + v.w;
    }
    #pragma unroll
    for (int off = 32; off >= 1; off >>= 1) s += __shfl_xor(s, off);
    if (lane == 0) ws[GATEIN_OFF + bid] = s * (1.f / (HIN * WIN));
}

// ---------------------------------------------------------------------------
// Kernel C: logits -> top2 -> softmax -> dense gates[b][4]
// ---------------------------------------------------------------------------
__global__ void gate_kernel(const float* __restrict__ w_gate, float* __restrict__ ws) {
    int b = threadIdx.x;
    if (b >= NB) return;
    const float* gi = ws + GATEIN_OFF + b * NC1;
    float l[NE] = {0.f, 0.f, 0.f, 0.f};
    for (int c = 0; c < NC1; ++c) {
        float v = gi[c];
        #pragma unroll
        for (int e = 0; e < NE; ++e) l[e] += v * w_gate[c * NE + e];
    }
    int i0 = 0; float v0 = l[0];
    #pragma unroll
    for (int e = 1; e < NE; ++e) if (l[e] > v0) { v0 = l[e]; i0 = e; }
    int i1 = -1; float v1 = -3.4e38f;
    #pragma unroll
    for (int e = 0; e < NE; ++e) if (e != i0 && l[e] > v1) { v1 = l[e]; i1 = e; }
    float e1 = expf(v1 - v0);
    float denom = 1.f + e1;
    float g0 = 1.f / denom, g1 = e1 / denom;
    #pragma unroll
    for (int e = 0; e < NE; ++e)
        ws[GATES_OFF + b * NE + e] = (e == i0) ? g0 : ((e == i1) ? g1 : 0.f);
}

// ---------------------------------------------------------------------------
// Kernel D: MFMA implicit-GEMM conv + LN + gated combine.
// Block = (b, h'), 256 threads = 4 waves.
// Wave w: c2 rows [w*32, w*32+32), all 32 w' columns.
// LDS x tile: xs[r][p][c] bf16, p = w_in+1 in [0,64], with 16B-unit swizzle
//   ps = (c>>3) ^ ((p>>1)&7)  (write side == read side).
// ---------------------------------------------------------------------------
#define XS_IDX(r, p, ps, c7) ((((r) * 65 + (p)) << 6) + ((ps) << 3) + (c7))

__global__ __launch_bounds__(256, 4) void fused_kernel(
        const float* __restrict__ x,
        const float* __restrict__ ws,
        float* __restrict__ out) {
    __shared__ __bf16 xs[3 * 65 * 64];          // 24960 B
    __shared__ float  red[3 * 2 * 4 * 32];      // 3072 B: [slot][sum/sq][wave][col]

    const int bid = blockIdx.x;
    const int b   = bid >> 5;
    const int hp  = bid & 31;
    const int tid = threadIdx.x;
    const int ln  = tid & 63;
    const int wv  = tid >> 6;          // wave 0..3
    const int cl  = ln & 31;           // w' column / c2-within-tile row sel
    const int hl  = ln >> 5;           // k-half
    const int wbase = wv * 32;         // c2 base for this wave

    // ---- stage: transpose+convert 3 input rows into LDS ----
    {
        const int c    = tid & 63;
        const int wseg = tid >> 6;     // 0..3, covers w = wseg*16 .. +15
        #pragma unroll
        for (int r = 0; r < 3; ++r) {
            int hin = 2 * hp - 1 + r;
            const float* src = x + (((size_t)b * NC1 + c) * HIN + hin) * WIN + wseg * 16;
            #pragma unroll
            for (int i = 0; i < 4; ++i) {
                float4 v = make_float4(0.f, 0.f, 0.f, 0.f);
                if (hin >= 0) v = *(const float4*)(src + i * 4);
                #pragma unroll
                for (int k = 0; k < 4; ++k) {
                    int w = wseg * 16 + i * 4 + k;
                    int p = w + 1;
                    int ps = (c >> 3) ^ ((p >> 1) & 7);
                    float f = (k == 0) ? v.x : (k == 1) ? v.y : (k == 2) ? v.z : v.w;
                    xs[XS_IDX(r, p, ps, c & 7)] = (__bf16)f;
                }
            }
        }
        if (tid < 64) {   // zero left-pad column p=0 (swizzle(0)=identity)
            #pragma unroll
            for (int r = 0; r < 3; ++r) xs[XS_IDX(r, 0, (tid >> 3), tid & 7)] = (__bf16)0.f;
        }
    }

    // ---- gates for this sample: 2 routed slots + shared ----
    const float* gp = ws + GATES_OFF + b * NE;
    int s0 = -1, s1 = -1; float ga = 0.f, gb = 0.f;
    #pragma unroll
    for (int e = 0; e < NE; ++e) {
        float ge = gp[e];
        if (ge > 0.f) { if (s0 < 0) { s0 = e; ga = ge; } else if (s1 < 0) { s1 = e; gb = ge; } }
    }
    if (s0 < 0) { s0 = 0; ga = 0.f; }
    if (s1 < 0) { s1 = (s0 == 0) ? 1 : 0; gb = 0.f; }

    // ---- init accumulators with bias (rows rowbase+{0..3,8..11,16..19,24..27}) ----
    const int rowbase = wbase + 4 * hl;
    f32x16 acc0, acc1, acc2;
    #define INIT_ACC(ACC, SID)                                                  \
    {                                                                           \
        const float4* bp = (const float4*)(ws + BIAS_OFF + (SID) * NC2 + rowbase); \
        float4 b0 = bp[0], b1 = bp[2], b2 = bp[4], b3 = bp[6];                  \
        ACC[0]=b0.x; ACC[1]=b0.y; ACC[2]=b0.z; ACC[3]=b0.w;                     \
        ACC[4]=b1.x; ACC[5]=b1.y; ACC[6]=b1.z; ACC[7]=b1.w;                     \
        ACC[8]=b2.x; ACC[9]=b2.y; ACC[10]=b2.z; ACC[11]=b2.w;                   \
        ACC[12]=b3.x; ACC[13]=b3.y; ACC[14]=b3.z; ACC[15]=b3.w;                 \
    }
    INIT_ACC(acc0, s0)
    INIT_ACC(acc1, s1)
    INIT_ACC(acc2, 4)

    __syncthreads();

    // ---- main loop: 9 taps x (4 k-steps x 3 slots) MFMAs ----
    const __bf16* wA = (const __bf16*)(ws + WBF_OFF);
    const int p_l = 2 * cl;            // + kw
    #define SLOT_MFMA(ACC, SID)                                                   \
    {                                                                             \
        const __bf16* ap = wA + (((size_t)(SID) * 9 + tap) * NC2 + wbase + cl) * NC1 + hl * 8; \
        bf16x8 a0 = *(const bf16x8*)(ap);                                         \
        bf16x8 a1 = *(const bf16x8*)(ap + 16);                                    \
        bf16x8 a2 = *(const bf16x8*)(ap + 32);                                    \
        bf16x8 a3 = *(const bf16x8*)(ap + 48);                                    \
        ACC = __builtin_amdgcn_mfma_f32_32x32x16_bf16(a0, bf0, ACC, 0, 0, 0);     \
        ACC = __builtin_amdgcn_mfma_f32_32x32x16_bf16(a1, bf1, ACC, 0, 0, 0);     \
        ACC = __builtin_amdgcn_mfma_f32_32x32x16_bf16(a2, bf2, ACC, 0, 0, 0);     \
        ACC = __builtin_amdgcn_mfma_f32_32x32x16_bf16(a3, bf3, ACC, 0, 0, 0);     \
    }
    #pragma unroll
    for (int r = 0; r < 3; ++r) {
        #pragma unroll
        for (int kw = 0; kw < 3; ++kw) {
            const int tap = r * 3 + kw;
            const int p   = p_l + kw;
            const int swb = (p >> 1) & 7;
            bf16x8 bf0 = *(const bf16x8*)&xs[XS_IDX(r, p, (0 * 2 + hl) ^ swb, 0)];
            bf16x8 bf1 = *(const bf16x8*)&xs[XS_IDX(r, p, (1 * 2 + hl) ^ swb, 0)];
            bf16x8 bf2 = *(const bf16x8*)&xs[XS_IDX(r, p, (2 * 2 + hl) ^ swb, 0)];
            bf16x8 bf3 = *(const bf16x8*)&xs[XS_IDX(r, p, (3 * 2 + hl) ^ swb, 0)];
            SLOT_MFMA(acc0, s0)
            SLOT_MFMA(acc1, s1)
            SLOT_MFMA(acc2, 4)
        }
    }

    // ---- per-slot LN + gated accumulate ----
    float fin[16];
    #pragma unroll
    for (int i = 0; i < 16; ++i) fin[i] = 0.f;

    #define SLOT_LN(ACC, SID, G, SLOTIDX)                                         \
    {                                                                             \
        float sum = 0.f, sq = 0.f;                                                \
        _Pragma("unroll")                                                         \
        for (int i = 0; i < 16; ++i) { float a = ACC[i]; sum += a; sq += a * a; } \
        sum += __shfl_xor(sum, 32); sq += __shfl_xor(sq, 32);                     \
        if (ln < 32) {                                                            \
            red[(((SLOTIDX) * 2 + 0) * 4 + wv) * 32 + cl] = sum;                  \
            red[(((SLOTIDX) * 2 + 1) * 4 + wv) * 32 + cl] = sq;                   \
        }                                                                         \
        __syncthreads();                                                          \
        float tot = 0.f, totq = 0.f;                                              \
        _Pragma("unroll")                                                         \
        for (int w = 0; w < 4; ++w) {                                             \
            tot  += red[(((SLOTIDX) * 2 + 0) * 4 + w) * 32 + cl];                 \
            totq += red[(((SLOTIDX) * 2 + 1) * 4 + w) * 32 + cl];                 \
        }                                                                         \
        float mean = tot * (1.f / NC2);                                           \
        float var  = totq * (1.f / NC2) - mean * mean;                            \
        float rstd = rsqrtf(var + 1e-6f);                                         \
        const float4* gmp = (const float4*)(ws + GAMMA_OFF + (SID) * NC2 + rowbase); \
        const float4* btp = (const float4*)(ws + BETA_OFF  + (SID) * NC2 + rowbase); \
        float4 g0 = gmp[0], g1 = gmp[2], g2 = gmp[4], g3 = gmp[6];                \
        float4 t0 = btp[0], t1 = btp[2], t2 = btp[4], t3 = btp[6];                \
        float gm[16] = {g0.x,g0.y,g0.z,g0.w, g1.x,g1.y,g1.z,g1.w,                 \
                        g2.x,g2.y,g2.z,g2.w, g3.x,g3.y,g3.z,g3.w};                \
        float bt[16] = {t0.x,t0.y,t0.z,t0.w, t1.x,t1.y,t1.z,t1.w,                 \
                        t2.x,t2.y,t2.z,t2.w, t3.x,t3.y,t3.z,t3.w};                \
        _Pragma("unroll")                                                         \
        for (int i = 0; i < 16; ++i) {                                            \
            float nrm = (ACC[i] - mean) * rstd;                                   \
            fin[i] = fmaf((G), fmaf(gm[i], nrm, bt[i]), fin[i]);                  \
        }                                                                         \
    }
    SLOT_LN(acc0, s0, ga, 0)
    SLOT_LN(acc1, s1, gb, 1)
    SLOT_LN(acc2, 4, 1.0f, 2)

    // ---- store: out[b][c2][hp][cl], c2 = rowbase + (reg&3) + 8*(reg>>2) ----
    float* ob = out + (size_t)b * (NC2 * HOUT * WOUT) + hp * WOUT + cl;
    #pragma unroll
    for (int i = 0; i < 16; ++i) {
        int c2 = rowbase + (i & 3) + 8 * (i >> 2);
        ob[(size_t)c2 * (HOUT * WOUT)] = fin[i];
    }
}

// ---------------------------------------------------------------------------
extern "C" void kernel_launch(void* const* d_in, const int* in_sizes, int n_in,
                              void* d_out, int out_size, void* d_ws, size_t ws_size,
                              hipStream_t stream) {
    const float* x        = (const float*)d_in[0];
    const float* w_gate   = (const float*)d_in[1];
    const float* expert_w = (const float*)d_in[2];
    const float* expert_b = (const float*)d_in[3];
    const float* eln_w    = (const float*)d_in[4];
    const float* eln_b    = (const float*)d_in[5];
    const float* shared_w = (const float*)d_in[6];
    const float* shared_b = (const float*)d_in[7];
    const float* sln_w    = (const float*)d_in[8];
    const float* sln_b    = (const float*)d_in[9];
    float* ws  = (float*)d_ws;
    float* out = (float*)d_out;

    prep_kernel<<<1440, 256, 0, stream>>>(expert_w, shared_w, expert_b, shared_b,
                                          eln_w, sln_w, eln_b, sln_b, ws);
    gatein_kernel<<<NB * NC1, 64, 0, stream>>>(x, ws);
    gate_kernel<<<1, 64, 0, stream>>>(w_gate, ws);
    fused_kernel<<<NB * HOUT, 256, 0, stream>>>(x, ws, out);
}

// Round 3
// 49.404 us; speedup vs baseline: 5.5069x; 1.7624x over previous
//
#include <hip/hip_runtime.h>
#include <cstdint>
#include <cstddef>

// Problem constants
#define NB    32
#define NC1   64
#define NC2   128
#define NE    4
#define NSLOT 5
#define HIN   64
#define WIN   64
#define HOUT  32
#define WOUT  32

// ws layout (float offsets)
#define GATEIN_OFF 0        // [32][64] f32
#define GATES_OFF  2048     // [32][4]  f32
#define BIAS_OFF   2176     // [5][128] f32
#define GAMMA_OFF  2816     // [5][128] f32
#define BETA_OFF   3456     // [5][128] f32
#define WBF_OFF    4096     // bf16 frag table [5][9][4 wv][4 kk][64 lane][8]

typedef __bf16 bf16x8 __attribute__((ext_vector_type(8)));
typedef float  f32x16 __attribute__((ext_vector_type(16)));

// ---------------------------------------------------------------------------
// Kernel A: repack weights into MFMA-fragment order:
//   wfrag[((((s*9+tap)*4 + wv)*4 + kk)*64 + lane)*8 + j]
//     = W[s][c2 = wv*32 + (lane&31)][c = kk*16 + (lane>>5)*8 + j][tap]
// so a wave's A-frag load is 64 lanes x 16B contiguous (1 KB).
// ---------------------------------------------------------------------------
__global__ void prep_kernel(const float* __restrict__ expert_w,
                            const float* __restrict__ shared_w,
                            const float* __restrict__ expert_b,
                            const float* __restrict__ shared_b,
                            const float* __restrict__ eln_w,
                            const float* __restrict__ sln_w,
                            const float* __restrict__ eln_b,
                            const float* __restrict__ sln_b,
                            float* __restrict__ ws) {
    int i = blockIdx.x * 256 + threadIdx.x;
    if (i < NSLOT * 9 * 4 * 4 * 64 * 8) {
        int j    = i & 7;
        int l    = (i >> 3) & 63;
        int kk   = (i >> 9) & 3;
        int wv   = (i >> 11) & 3;
        int rest = i >> 13;
        int tap  = rest % 9;
        int e    = rest / 9;
        int c2 = wv * 32 + (l & 31);
        int c  = kk * 16 + (l >> 5) * 8 + j;
        float v;
        if (e < NE) v = expert_w[(((size_t)(e * NC2 + c2) * NC1 + c) * 9) + tap];
        else        v = shared_w[(((size_t)c2 * NC1 + c) * 9) + tap];
        ((__bf16*)(ws + WBF_OFF))[i] = (__bf16)v;
    }
    if (i < NSLOT * NC2) {
        int e = i >> 7, c2 = i & 127;
        ws[BIAS_OFF  + i] = (e < NE) ? expert_b[i] : shared_b[c2];
        ws[GAMMA_OFF + i] = (e < NE) ? eln_w[i]    : sln_w[c2];
        ws[BETA_OFF  + i] = (e < NE) ? eln_b[i]    : sln_b[c2];
    }
}

// ---------------------------------------------------------------------------
// Kernel B: gate_in[b][c] = mean over HxW.  One wave per (b,c).
// ---------------------------------------------------------------------------
__global__ void gatein_kernel(const float* __restrict__ x, float* __restrict__ ws) {
    int bid  = blockIdx.x;
    int lane = threadIdx.x;
    const float* src = x + (size_t)bid * (HIN * WIN);
    float s = 0.f;
    for (int i = lane * 4; i < HIN * WIN; i += 64 * 4) {
        float4 v = *(const float4*)(src + i);
        s += v.x + v.y + v.z + v.w;
    }
    #pragma unroll
    for (int off = 32; off >= 1; off >>= 1) s += __shfl_xor(s, off);
    if (lane == 0) ws[GATEIN_OFF + bid] = s * (1.f / (HIN * WIN));
}

// ---------------------------------------------------------------------------
// Kernel C: logits -> top2 -> softmax -> dense gates[b][4]
// ---------------------------------------------------------------------------
__global__ void gate_kernel(const float* __restrict__ w_gate, float* __restrict__ ws) {
    int b = threadIdx.x;
    if (b >= NB) return;
    const float* gi = ws + GATEIN_OFF + b * NC1;
    float l[NE] = {0.f, 0.f, 0.f, 0.f};
    for (int c = 0; c < NC1; ++c) {
        float v = gi[c];
        #pragma unroll
        for (int e = 0; e < NE; ++e) l[e] += v * w_gate[c * NE + e];
    }
    int i0 = 0; float v0 = l[0];
    #pragma unroll
    for (int e = 1; e < NE; ++e) if (l[e] > v0) { v0 = l[e]; i0 = e; }
    int i1 = -1; float v1 = -3.4e38f;
    #pragma unroll
    for (int e = 0; e < NE; ++e) if (e != i0 && l[e] > v1) { v1 = l[e]; i1 = e; }
    float e1 = expf(v1 - v0);
    float denom = 1.f + e1;
    float g0 = 1.f / denom, g1 = e1 / denom;
    #pragma unroll
    for (int e = 0; e < NE; ++e)
        ws[GATES_OFF + b * NE + e] = (e == i0) ? g0 : ((e == i1) ? g1 : 0.f);
}

// ---------------------------------------------------------------------------
// Kernel D: MFMA implicit-GEMM conv + LN + gated combine, HTILE=2.
// Block = (b, hg) with hg covering h' = 2hg, 2hg+1. 256 threads = 4 waves.
// Wave wv: c2 rows [wv*32, wv*32+32), all 32 w' columns, BOTH h' rows.
// LDS xs[r][p][c] bf16, r in [0,5) local rows (hin = 4hg-1+r), p = w_in+1,
// 16B-unit swizzle ps = (c>>3) ^ ((p>>1)&7) (write == read).
// ---------------------------------------------------------------------------
#define XS_IDX(r, p, ps, c7) ((((r) * 65 + (p)) << 6) + ((ps) << 3) + (c7))

__global__ __launch_bounds__(256, 2) void fused_kernel(
        const float* __restrict__ x,
        const float* __restrict__ ws,
        float* __restrict__ out) {
    __shared__ __bf16 xs[5 * 65 * 64];      // 41600 B
    __shared__ float  red[6 * 2 * 128];     // 6144 B: [slot*2+t][sum/sq][wv*32+cl]

    const int bid = blockIdx.x;             // 0..511
    const int b   = bid >> 4;
    const int hg  = bid & 15;               // h' pair = 2hg, 2hg+1
    const int tid = threadIdx.x;
    const int ln  = tid & 63;
    const int wv  = tid >> 6;
    const int cl  = ln & 31;
    const int hl  = ln >> 5;
    const int wbase = wv * 32;

    // ---- stage 5 input rows, coalesced: 16 lanes cover one channel row ----
    #pragma unroll
    for (int r = 0; r < 5; ++r) {
        const int hin = 4 * hg - 1 + r;
        #pragma unroll
        for (int pass = 0; pass < 4; ++pass) {
            int idx = (pass << 8) + tid;    // 0..1023
            int c   = idx >> 4;
            int i4  = idx & 15;
            float4 v = make_float4(0.f, 0.f, 0.f, 0.f);
            if (hin >= 0)
                v = *(const float4*)(x + (((size_t)b * NC1 + c) * HIN + hin) * WIN + i4 * 4);
            #pragma unroll
            for (int k = 0; k < 4; ++k) {
                int p  = i4 * 4 + k + 1;
                int ps = (c >> 3) ^ ((p >> 1) & 7);
                float f = (k == 0) ? v.x : (k == 1) ? v.y : (k == 2) ? v.z : v.w;
                xs[XS_IDX(r, p, ps, c & 7)] = (__bf16)f;
            }
        }
    }
    if (tid < 64) {   // zero left-pad column p=0 for all 5 rows
        #pragma unroll
        for (int r = 0; r < 5; ++r) xs[XS_IDX(r, 0, (tid >> 3), tid & 7)] = (__bf16)0.f;
    }

    // ---- gates: 2 routed slots + shared ----
    const float* gp = ws + GATES_OFF + b * NE;
    int s0 = -1, s1 = -1; float ga = 0.f, gb = 0.f;
    #pragma unroll
    for (int e = 0; e < NE; ++e) {
        float ge = gp[e];
        if (ge > 0.f) { if (s0 < 0) { s0 = e; ga = ge; } else if (s1 < 0) { s1 = e; gb = ge; } }
    }
    if (s0 < 0) { s0 = 0; ga = 0.f; }
    if (s1 < 0) { s1 = (s0 == 0) ? 1 : 0; gb = 0.f; }

    // ---- init 6 accumulators with bias ----
    const int rowbase = wbase + 4 * hl;
    f32x16 accA0, accA1, accA2, accB0, accB1, accB2;
    #define INIT_ACC(ACC, SID)                                                  \
    {                                                                           \
        const float4* bp = (const float4*)(ws + BIAS_OFF + (SID) * NC2 + rowbase); \
        float4 b0 = bp[0], b1 = bp[2], b2 = bp[4], b3 = bp[6];                  \
        ACC[0]=b0.x; ACC[1]=b0.y; ACC[2]=b0.z; ACC[3]=b0.w;                     \
        ACC[4]=b1.x; ACC[5]=b1.y; ACC[6]=b1.z; ACC[7]=b1.w;                     \
        ACC[8]=b2.x; ACC[9]=b2.y; ACC[10]=b2.z; ACC[11]=b2.w;                   \
        ACC[12]=b3.x; ACC[13]=b3.y; ACC[14]=b3.z; ACC[15]=b3.w;                 \
    }
    INIT_ACC(accA0, s0) INIT_ACC(accA1, s1) INIT_ACC(accA2, 4)
    INIT_ACC(accB0, s0) INIT_ACC(accB1, s1) INIT_ACC(accB2, 4)

    __syncthreads();

    // ---- main loop: 9 taps x (4 kk x 3 slots x 2 h') MFMAs ----
    const __bf16* wA = (const __bf16*)(ws + WBF_OFF);
    const int p_l = 2 * cl;
    #define MFMA(A, B, C) C = __builtin_amdgcn_mfma_f32_32x32x16_bf16(A, B, C, 0, 0, 0)
    #define DO_TAP(R_, KW_)                                                        \
    {                                                                              \
        const int tap = (R_) * 3 + (KW_);                                          \
        const int p   = p_l + (KW_);                                              \
        const int swb = (p >> 1) & 7;                                              \
        bf16x8 bA0 = *(const bf16x8*)&xs[XS_IDX((R_),     p, (0 + hl) ^ swb, 0)];  \
        bf16x8 bA1 = *(const bf16x8*)&xs[XS_IDX((R_),     p, (2 + hl) ^ swb, 0)];  \
        bf16x8 bA2 = *(const bf16x8*)&xs[XS_IDX((R_),     p, (4 + hl) ^ swb, 0)];  \
        bf16x8 bA3 = *(const bf16x8*)&xs[XS_IDX((R_),     p, (6 + hl) ^ swb, 0)];  \
        bf16x8 bB0 = *(const bf16x8*)&xs[XS_IDX((R_) + 2, p, (0 + hl) ^ swb, 0)];  \
        bf16x8 bB1 = *(const bf16x8*)&xs[XS_IDX((R_) + 2, p, (2 + hl) ^ swb, 0)];  \
        bf16x8 bB2 = *(const bf16x8*)&xs[XS_IDX((R_) + 2, p, (4 + hl) ^ swb, 0)];  \
        bf16x8 bB3 = *(const bf16x8*)&xs[XS_IDX((R_) + 2, p, (6 + hl) ^ swb, 0)];  \
        const __bf16* ap0 = wA + (((size_t)s0 * 9 + tap) * 4 + wv) * 2048 + ln * 8; \
        const __bf16* ap1 = wA + (((size_t)s1 * 9 + tap) * 4 + wv) * 2048 + ln * 8; \
        const __bf16* ap2 = wA + (((size_t)4  * 9 + tap) * 4 + wv) * 2048 + ln * 8; \
        bf16x8 a00 = *(const bf16x8*)(ap0),        a01 = *(const bf16x8*)(ap0 + 512); \
        bf16x8 a02 = *(const bf16x8*)(ap0 + 1024), a03 = *(const bf16x8*)(ap0 + 1536); \
        bf16x8 a10 = *(const bf16x8*)(ap1),        a11 = *(const bf16x8*)(ap1 + 512); \
        bf16x8 a12 = *(const bf16x8*)(ap1 + 1024), a13 = *(const bf16x8*)(ap1 + 1536); \
        bf16x8 a20 = *(const bf16x8*)(ap2),        a21 = *(const bf16x8*)(ap2 + 512); \
        bf16x8 a22 = *(const bf16x8*)(ap2 + 1024), a23 = *(const bf16x8*)(ap2 + 1536); \
        MFMA(a00, bA0, accA0); MFMA(a00, bB0, accB0);                              \
        MFMA(a10, bA0, accA1); MFMA(a10, bB0, accB1);                              \
        MFMA(a20, bA0, accA2); MFMA(a20, bB0, accB2);                              \
        MFMA(a01, bA1, accA0); MFMA(a01, bB1, accB0);                              \
        MFMA(a11, bA1, accA1); MFMA(a11, bB1, accB1);                              \
        MFMA(a21, bA1, accA2); MFMA(a21, bB1, accB2);                              \
        MFMA(a02, bA2, accA0); MFMA(a02, bB2, accB0);                              \
        MFMA(a12, bA2, accA1); MFMA(a12, bB2, accB1);                              \
        MFMA(a22, bA2, accA2); MFMA(a22, bB2, accB2);                              \
        MFMA(a03, bA3, accA0); MFMA(a03, bB3, accB0);                              \
        MFMA(a13, bA3, accA1); MFMA(a13, bB3, accB1);                              \
        MFMA(a23, bA3, accA2); MFMA(a23, bB3, accB2);                              \
    }
    DO_TAP(0, 0) DO_TAP(0, 1) DO_TAP(0, 2)
    DO_TAP(1, 0) DO_TAP(1, 1) DO_TAP(1, 2)
    DO_TAP(2, 0) DO_TAP(2, 1) DO_TAP(2, 2)

    // ---- LN reductions: all 6 partials, one barrier ----
    #define PUT_RED(ACC, SI, T)                                                   \
    {                                                                             \
        float sum = 0.f, sq = 0.f;                                                \
        _Pragma("unroll")                                                         \
        for (int i = 0; i < 16; ++i) { float a = ACC[i]; sum += a; sq += a * a; } \
        sum += __shfl_xor(sum, 32); sq += __shfl_xor(sq, 32);                     \
        if (ln < 32) {                                                            \
            red[(((SI) * 2 + (T)) * 2 + 0) * 128 + wbase + cl] = sum;             \
            red[(((SI) * 2 + (T)) * 2 + 1) * 128 + wbase + cl] = sq;              \
        }                                                                         \
    }
    PUT_RED(accA0, 0, 0) PUT_RED(accB0, 0, 1)
    PUT_RED(accA1, 1, 0) PUT_RED(accB1, 1, 1)
    PUT_RED(accA2, 2, 0) PUT_RED(accB2, 2, 1)
    __syncthreads();

    float finA[16], finB[16];
    #pragma unroll
    for (int i = 0; i < 16; ++i) { finA[i] = 0.f; finB[i] = 0.f; }

    #define APPLY(ACC, FIN, SI, T, GM, BT, G)                                     \
    {                                                                             \
        float tot = 0.f, totq = 0.f;                                              \
        _Pragma("unroll")                                                         \
        for (int w = 0; w < 4; ++w) {                                             \
            tot  += red[(((SI) * 2 + (T)) * 2 + 0) * 128 + w * 32 + cl];          \
            totq += red[(((SI) * 2 + (T)) * 2 + 1) * 128 + w * 32 + cl];          \
        }                                                                         \
        float mean = tot * (1.f / NC2);                                           \
        float var  = totq * (1.f / NC2) - mean * mean;                            \
        float rstd = rsqrtf(var + 1e-6f);                                         \
        _Pragma("unroll")                                                         \
        for (int i = 0; i < 16; ++i) {                                            \
            float nrm = (ACC[i] - mean) * rstd;                                   \
            FIN[i] = fmaf((G), fmaf(GM[i], nrm, BT[i]), FIN[i]);                  \
        }                                                                         \
    }
    #define LOAD_GB(SID, GM, BT)                                                  \
        float GM[16], BT[16];                                                     \
        {                                                                         \
            const float4* gmp = (const float4*)(ws + GAMMA_OFF + (SID) * NC2 + rowbase); \
            const float4* btp = (const float4*)(ws + BETA_OFF  + (SID) * NC2 + rowbase); \
            float4 g0 = gmp[0], g1 = gmp[2], g2 = gmp[4], g3 = gmp[6];            \
            float4 t0 = btp[0], t1 = btp[2], t2 = btp[4], t3 = btp[6];            \
            GM[0]=g0.x;GM[1]=g0.y;GM[2]=g0.z;GM[3]=g0.w;GM[4]=g1.x;GM[5]=g1.y;GM[6]=g1.z;GM[7]=g1.w; \
            GM[8]=g2.x;GM[9]=g2.y;GM[10]=g2.z;GM[11]=g2.w;GM[12]=g3.x;GM[13]=g3.y;GM[14]=g3.z;GM[15]=g3.w; \
            BT[0]=t0.x;BT[1]=t0.y;BT[2]=t0.z;BT[3]=t0.w;BT[4]=t1.x;BT[5]=t1.y;BT[6]=t1.z;BT[7]=t1.w; \
            BT[8]=t2.x;BT[9]=t2.y;BT[10]=t2.z;BT[11]=t2.w;BT[12]=t3.x;BT[13]=t3.y;BT[14]=t3.z;BT[15]=t3.w; \
        }
    {
        LOAD_GB(s0, gm0, bt0)
        APPLY(accA0, finA, 0, 0, gm0, bt0, ga)
        APPLY(accB0, finB, 0, 1, gm0, bt0, ga)
    }
    {
        LOAD_GB(s1, gm1, bt1)
        APPLY(accA1, finA, 1, 0, gm1, bt1, gb)
        APPLY(accB1, finB, 1, 1, gm1, bt1, gb)
    }
    {
        LOAD_GB(4, gm2, bt2)
        APPLY(accA2, finA, 2, 0, gm2, bt2, 1.0f)
        APPLY(accB2, finB, 2, 1, gm2, bt2, 1.0f)
    }

    // ---- store both h' rows ----
    {
        float* ob = out + (size_t)b * (NC2 * HOUT * WOUT) + (2 * hg) * WOUT + cl;
        #pragma unroll
        for (int i = 0; i < 16; ++i) {
            int c2 = rowbase + (i & 3) + 8 * (i >> 2);
            ob[(size_t)c2 * (HOUT * WOUT)] = finA[i];
        }
        ob += WOUT;
        #pragma unroll
        for (int i = 0; i < 16; ++i) {
            int c2 = rowbase + (i & 3) + 8 * (i >> 2);
            ob[(size_t)c2 * (HOUT * WOUT)] = finB[i];
        }
    }
}

// ---------------------------------------------------------------------------
extern "C" void kernel_launch(void* const* d_in, const int* in_sizes, int n_in,
                              void* d_out, int out_size, void* d_ws, size_t ws_size,
                              hipStream_t stream) {
    const float* x        = (const float*)d_in[0];
    const float* w_gate   = (const float*)d_in[1];
    const float* expert_w = (const float*)d_in[2];
    const float* expert_b = (const float*)d_in[3];
    const float* eln_w    = (const float*)d_in[4];
    const float* eln_b    = (const float*)d_in[5];
    const float* shared_w = (const float*)d_in[6];
    const float* shared_b = (const float*)d_in[7];
    const float* sln_w    = (const float*)d_in[8];
    const float* sln_b    = (const float*)d_in[9];
    float* ws  = (float*)d_ws;
    float* out = (float*)d_out;

    prep_kernel<<<1440, 256, 0, stream>>>(expert_w, shared_w, expert_b, shared_b,
                                          eln_w, sln_w, eln_b, sln_b, ws);
    gatein_kernel<<<NB * NC1, 64, 0, stream>>>(x, ws);
    gate_kernel<<<1, 64, 0, stream>>>(w_gate, ws);
    fused_kernel<<<NB * 16, 256, 0, stream>>>(x, ws, out);
}

// Round 4
// 48.025 us; speedup vs baseline: 5.6650x; 1.0287x over previous
//
#include <hip/hip_runtime.h>
#include <cstdint>
#include <cstddef>

// Problem constants
#define NB    32
#define NC1   64
#define NC2   128
#define NE    4
#define NSLOT 5
#define HIN   64
#define WIN   64
#define HOUT  32
#define WOUT  32

// ws layout (float offsets)
#define GATEIN_OFF 0        // [32][64] f32
#define GATES_OFF  2048     // [32][4]  f32
#define BIAS_OFF   2176     // [5][128] f32
#define GAMMA_OFF  2816     // [5][128] f32
#define BETA_OFF   3456     // [5][128] f32
#define WBF_OFF    4096     // bf16 frag table [5][9][4 wv][4 kk][64 lane][8]

typedef __bf16 bf16x8 __attribute__((ext_vector_type(8)));
typedef float  f32x16 __attribute__((ext_vector_type(16)));

// ---------------------------------------------------------------------------
// Kernel A (merged): blocks [0,1440): weight/bias repack into MFMA frag order
//   wfrag[((((s*9+tap)*4 + wv)*4 + kk)*64 + lane)*8 + j]
//     = W[s][c2 = wv*32 + (lane&31)][c = kk*16 + (lane>>5)*8 + j][tap]
// blocks [1440,1952): gate_in[b][c] row means (one wave per (b,c) row).
// ---------------------------------------------------------------------------
__global__ void prep2_kernel(const float* __restrict__ x,
                             const float* __restrict__ expert_w,
                             const float* __restrict__ shared_w,
                             const float* __restrict__ expert_b,
                             const float* __restrict__ shared_b,
                             const float* __restrict__ eln_w,
                             const float* __restrict__ sln_w,
                             const float* __restrict__ eln_b,
                             const float* __restrict__ sln_b,
                             float* __restrict__ ws) {
    int bid = blockIdx.x;
    if (bid < 1440) {
        int i = bid * 256 + threadIdx.x;
        {
            int j    = i & 7;
            int l    = (i >> 3) & 63;
            int kk   = (i >> 9) & 3;
            int wv   = (i >> 11) & 3;
            int rest = i >> 13;
            int tap  = rest % 9;
            int e    = rest / 9;
            int c2 = wv * 32 + (l & 31);
            int c  = kk * 16 + (l >> 5) * 8 + j;
            float v;
            if (e < NE) v = expert_w[(((size_t)(e * NC2 + c2) * NC1 + c) * 9) + tap];
            else        v = shared_w[(((size_t)c2 * NC1 + c) * 9) + tap];
            ((__bf16*)(ws + WBF_OFF))[i] = (__bf16)v;
        }
        if (i < NSLOT * NC2) {
            int e = i >> 7, c2 = i & 127;
            ws[BIAS_OFF  + i] = (e < NE) ? expert_b[i] : shared_b[c2];
            ws[GAMMA_OFF + i] = (e < NE) ? eln_w[i]    : sln_w[c2];
            ws[BETA_OFF  + i] = (e < NE) ? eln_b[i]    : sln_b[c2];
        }
    } else {
        int row  = (bid - 1440) * 4 + (threadIdx.x >> 6);   // b*64 + c, 0..2047
        int lane = threadIdx.x & 63;
        const float* src = x + (size_t)row * (HIN * WIN);
        float s = 0.f;
        for (int i = lane * 4; i < HIN * WIN; i += 64 * 4) {
            float4 v = *(const float4*)(src + i);
            s += v.x + v.y + v.z + v.w;
        }
        #pragma unroll
        for (int off = 32; off >= 1; off >>= 1) s += __shfl_xor(s, off);
        if (lane == 0) ws[GATEIN_OFF + row] = s * (1.f / (HIN * WIN));
    }
}

// ---------------------------------------------------------------------------
// Kernel C: logits -> top2 -> softmax -> dense gates[b][4]
// ---------------------------------------------------------------------------
__global__ void gate_kernel(const float* __restrict__ w_gate, float* __restrict__ ws) {
    int b = threadIdx.x;
    if (b >= NB) return;
    const float* gi = ws + GATEIN_OFF + b * NC1;
    float l[NE] = {0.f, 0.f, 0.f, 0.f};
    for (int c = 0; c < NC1; ++c) {
        float v = gi[c];
        #pragma unroll
        for (int e = 0; e < NE; ++e) l[e] += v * w_gate[c * NE + e];
    }
    int i0 = 0; float v0 = l[0];
    #pragma unroll
    for (int e = 1; e < NE; ++e) if (l[e] > v0) { v0 = l[e]; i0 = e; }
    int i1 = -1; float v1 = -3.4e38f;
    #pragma unroll
    for (int e = 0; e < NE; ++e) if (e != i0 && l[e] > v1) { v1 = l[e]; i1 = e; }
    float e1 = expf(v1 - v0);
    float denom = 1.f + e1;
    float g0 = 1.f / denom, g1 = e1 / denom;
    #pragma unroll
    for (int e = 0; e < NE; ++e)
        ws[GATES_OFF + b * NE + e] = (e == i0) ? g0 : ((e == i1) ? g1 : 0.f);
}

// ---------------------------------------------------------------------------
// Kernel D: MFMA implicit-GEMM conv + LN + gated combine.
// Block = (b, hg), 512 threads = 8 waves. Wave-group t = wv8>>2 handles
// h' = 2hg + t; within group, wave wv = wv8&3 owns c2 rows [wv*32, +32).
// LDS xs[r][p][c] bf16, r in [0,5) (hin = 4hg-1+r), p = w_in+1,
// 16B-unit swizzle ps = (c>>3) ^ ((p>>1)&7) (write == read).
// ---------------------------------------------------------------------------
#define XS_IDX(r, p, ps, c7) ((((r) * 65 + (p)) << 6) + ((ps) << 3) + (c7))

__global__ __launch_bounds__(512, 4) void fused_kernel(
        const float* __restrict__ x,
        const float* __restrict__ ws,
        float* __restrict__ out) {
    __shared__ __bf16 xs[5 * 65 * 64];      // 41600 B
    __shared__ float  red[6 * 2 * 128];     // 6144 B: [slot*2+t][sum/sq][wv*32+cl]

    const int bid = blockIdx.x;             // 0..511
    const int b   = bid >> 4;
    const int hg  = bid & 15;
    const int tid = threadIdx.x;
    const int ln  = tid & 63;
    const int wv8 = tid >> 6;               // 0..7
    const int t   = wv8 >> 2;               // h'-half
    const int wv  = wv8 & 3;                // c2 tile
    const int cl  = ln & 31;
    const int hl  = ln >> 5;
    const int wbase = wv * 32;

    // ---- stage 5 input rows, coalesced: 16 lanes per channel row ----
    #pragma unroll
    for (int r = 0; r < 5; ++r) {
        const int hin = 4 * hg - 1 + r;
        #pragma unroll
        for (int pass = 0; pass < 2; ++pass) {
            int idx = (pass << 9) + tid;    // 0..1023
            int c   = idx >> 4;
            int i4  = idx & 15;
            float4 v = make_float4(0.f, 0.f, 0.f, 0.f);
            if (hin >= 0)
                v = *(const float4*)(x + (((size_t)b * NC1 + c) * HIN + hin) * WIN + i4 * 4);
            #pragma unroll
            for (int k = 0; k < 4; ++k) {
                int p  = i4 * 4 + k + 1;
                int ps = (c >> 3) ^ ((p >> 1) & 7);
                float f = (k == 0) ? v.x : (k == 1) ? v.y : (k == 2) ? v.z : v.w;
                xs[XS_IDX(r, p, ps, c & 7)] = (__bf16)f;
            }
        }
    }
    if (tid < 64) {   // zero left-pad column p=0 for all 5 rows
        #pragma unroll
        for (int r = 0; r < 5; ++r) xs[XS_IDX(r, 0, (tid >> 3), tid & 7)] = (__bf16)0.f;
    }

    // ---- gates: 2 routed slots + shared ----
    const float* gp = ws + GATES_OFF + b * NE;
    int s0 = -1, s1 = -1; float ga = 0.f, gb = 0.f;
    #pragma unroll
    for (int e = 0; e < NE; ++e) {
        float ge = gp[e];
        if (ge > 0.f) { if (s0 < 0) { s0 = e; ga = ge; } else if (s1 < 0) { s1 = e; gb = ge; } }
    }
    if (s0 < 0) { s0 = 0; ga = 0.f; }
    if (s1 < 0) { s1 = (s0 == 0) ? 1 : 0; gb = 0.f; }

    // ---- init 3 accumulators with bias ----
    const int rowbase = wbase + 4 * hl;
    f32x16 acc0, acc1, acc2;
    #define INIT_ACC(ACC, SID)                                                  \
    {                                                                           \
        const float4* bp = (const float4*)(ws + BIAS_OFF + (SID) * NC2 + rowbase); \
        float4 b0 = bp[0], b1 = bp[2], b2 = bp[4], b3 = bp[6];                  \
        ACC[0]=b0.x; ACC[1]=b0.y; ACC[2]=b0.z; ACC[3]=b0.w;                     \
        ACC[4]=b1.x; ACC[5]=b1.y; ACC[6]=b1.z; ACC[7]=b1.w;                     \
        ACC[8]=b2.x; ACC[9]=b2.y; ACC[10]=b2.z; ACC[11]=b2.w;                   \
        ACC[12]=b3.x; ACC[13]=b3.y; ACC[14]=b3.z; ACC[15]=b3.w;                 \
    }
    INIT_ACC(acc0, s0) INIT_ACC(acc1, s1) INIT_ACC(acc2, 4)

    __syncthreads();

    // ---- main loop: 9 taps x 4 kk x 3 slots MFMAs (rows r = kh + 2t) ----
    const __bf16* wA = (const __bf16*)(ws + WBF_OFF);
    const int p_l = 2 * cl;
    const int rofs = 2 * t;
    #define MFMA(A, B, C) C = __builtin_amdgcn_mfma_f32_32x32x16_bf16(A, B, C, 0, 0, 0)
    #define DO_TAP(R_, KW_)                                                        \
    {                                                                              \
        const int tap = (R_) * 3 + (KW_);                                          \
        const int p   = p_l + (KW_);                                              \
        const int swb = (p >> 1) & 7;                                              \
        const __bf16* ap0 = wA + (((size_t)s0 * 9 + tap) * 4 + wv) * 2048 + ln * 8; \
        const __bf16* ap1 = wA + (((size_t)s1 * 9 + tap) * 4 + wv) * 2048 + ln * 8; \
        const __bf16* ap2 = wA + (((size_t)4  * 9 + tap) * 4 + wv) * 2048 + ln * 8; \
        _Pragma("unroll")                                                          \
        for (int kk = 0; kk < 4; ++kk) {                                           \
            bf16x8 bb = *(const bf16x8*)&xs[XS_IDX((R_) + rofs, p, (2 * kk + hl) ^ swb, 0)]; \
            bf16x8 a0 = *(const bf16x8*)(ap0 + kk * 512);                          \
            bf16x8 a1 = *(const bf16x8*)(ap1 + kk * 512);                          \
            bf16x8 a2 = *(const bf16x8*)(ap2 + kk * 512);                          \
            MFMA(a0, bb, acc0);                                                    \
            MFMA(a1, bb, acc1);                                                    \
            MFMA(a2, bb, acc2);                                                    \
        }                                                                          \
    }
    DO_TAP(0, 0) DO_TAP(0, 1) DO_TAP(0, 2)
    DO_TAP(1, 0) DO_TAP(1, 1) DO_TAP(1, 2)
    DO_TAP(2, 0) DO_TAP(2, 1) DO_TAP(2, 2)

    // ---- LN reductions: all slot partials, one barrier ----
    #define PUT_RED(ACC, SI)                                                      \
    {                                                                             \
        float sum = 0.f, sq = 0.f;                                                \
        _Pragma("unroll")                                                         \
        for (int i = 0; i < 16; ++i) { float a = ACC[i]; sum += a; sq += a * a; } \
        sum += __shfl_xor(sum, 32); sq += __shfl_xor(sq, 32);                     \
        if (ln < 32) {                                                            \
            red[(((SI) * 2 + t) * 2 + 0) * 128 + wbase + cl] = sum;               \
            red[(((SI) * 2 + t) * 2 + 1) * 128 + wbase + cl] = sq;                \
        }                                                                         \
    }
    PUT_RED(acc0, 0)
    PUT_RED(acc1, 1)
    PUT_RED(acc2, 2)
    __syncthreads();

    float fin[16];
    #pragma unroll
    for (int i = 0; i < 16; ++i) fin[i] = 0.f;

    #define APPLY(ACC, SI, GM, BT, G)                                             \
    {                                                                             \
        float tot = 0.f, totq = 0.f;                                              \
        _Pragma("unroll")                                                         \
        for (int w = 0; w < 4; ++w) {                                             \
            tot  += red[(((SI) * 2 + t) * 2 + 0) * 128 + w * 32 + cl];            \
            totq += red[(((SI) * 2 + t) * 2 + 1) * 128 + w * 32 + cl];            \
        }                                                                         \
        float mean = tot * (1.f / NC2);                                           \
        float var  = totq * (1.f / NC2) - mean * mean;                            \
        float rstd = rsqrtf(var + 1e-6f);                                         \
        _Pragma("unroll")                                                         \
        for (int i = 0; i < 16; ++i) {                                            \
            float nrm = (ACC[i] - mean) * rstd;                                   \
            fin[i] = fmaf((G), fmaf(GM[i], nrm, BT[i]), fin[i]);                  \
        }                                                                         \
    }
    #define LOAD_GB(SID, GM, BT)                                                  \
        float GM[16], BT[16];                                                     \
        {                                                                         \
            const float4* gmp = (const float4*)(ws + GAMMA_OFF + (SID) * NC2 + rowbase); \
            const float4* btp = (const float4*)(ws + BETA_OFF  + (SID) * NC2 + rowbase); \
            float4 g0 = gmp[0], g1 = gmp[2], g2 = gmp[4], g3 = gmp[6];            \
            float4 t0 = btp[0], t1 = btp[2], t2 = btp[4], t3 = btp[6];            \
            GM[0]=g0.x;GM[1]=g0.y;GM[2]=g0.z;GM[3]=g0.w;GM[4]=g1.x;GM[5]=g1.y;GM[6]=g1.z;GM[7]=g1.w; \
            GM[8]=g2.x;GM[9]=g2.y;GM[10]=g2.z;GM[11]=g2.w;GM[12]=g3.x;GM[13]=g3.y;GM[14]=g3.z;GM[15]=g3.w; \
            BT[0]=t0.x;BT[1]=t0.y;BT[2]=t0.z;BT[3]=t0.w;BT[4]=t1.x;BT[5]=t1.y;BT[6]=t1.z;BT[7]=t1.w; \
            BT[8]=t2.x;BT[9]=t2.y;BT[10]=t2.z;BT[11]=t2.w;BT[12]=t3.x;BT[13]=t3.y;BT[14]=t3.z;BT[15]=t3.w; \
        }
    {
        LOAD_GB(s0, gm0, bt0)
        APPLY(acc0, 0, gm0, bt0, ga)
    }
    {
        LOAD_GB(s1, gm1, bt1)
        APPLY(acc1, 1, gm1, bt1, gb)
    }
    {
        LOAD_GB(4, gm2, bt2)
        APPLY(acc2, 2, gm2, bt2, 1.0f)
    }

    // ---- store this wave's h' row ----
    {
        float* ob = out + (size_t)b * (NC2 * HOUT * WOUT) + (2 * hg + t) * WOUT + cl;
        #pragma unroll
        for (int i = 0; i < 16; ++i) {
            int c2 = rowbase + (i & 3) + 8 * (i >> 2);
            ob[(size_t)c2 * (HOUT * WOUT)] = fin[i];
        }
    }
}

// ---------------------------------------------------------------------------
extern "C" void kernel_launch(void* const* d_in, const int* in_sizes, int n_in,
                              void* d_out, int out_size, void* d_ws, size_t ws_size,
                              hipStream_t stream) {
    const float* x        = (const float*)d_in[0];
    const float* w_gate   = (const float*)d_in[1];
    const float* expert_w = (const float*)d_in[2];
    const float* expert_b = (const float*)d_in[3];
    const float* eln_w    = (const float*)d_in[4];
    const float* eln_b    = (const float*)d_in[5];
    const float* shared_w = (const float*)d_in[6];
    const float* shared_b = (const float*)d_in[7];
    const float* sln_w    = (const float*)d_in[8];
    const float* sln_b    = (const float*)d_in[9];
    float* ws  = (float*)d_ws;
    float* out = (float*)d_out;

    // A: repack (blocks 0..1439) + gate_in means (blocks 1440..1951)
    prep2_kernel<<<1952, 256, 0, stream>>>(x, expert_w, shared_w, expert_b, shared_b,
                                           eln_w, sln_w, eln_b, sln_b, ws);
    // C: gating
    gate_kernel<<<1, 64, 0, stream>>>(w_gate, ws);
    // D: fused conv+LN+combine (8 waves, h'-pair split across wave groups)
    fused_kernel<<<NB * 16, 512, 0, stream>>>(x, ws, out);
}